// Round 10
// baseline (53.138 us; speedup 1.0000x reference)
//
#include <hip/hip_runtime.h>

// Problem constants (match reference)
constexpr int Bn = 4, Dn = 128, Hn = 128, Wn = 128, Cn = 16;
constexpr int NPIX = Hn * Wn;  // 16384
constexpr int PS = 4;          // proto pixel-chunks per (b,d)
constexpr int CS = 8;          // count slices per batch (2048 px each)

// ws layout (floats), all plain stores every call, no zero-init, no memsets:
//   protoPart [Bn][PS][Dn][Cn] = 32768
//   countsPart[Bn][CS][Cn]     = 512
//   maskPart  [Bn][CS]         = 32
//   dummyOut  [1]              (sink for the duplicated probe dispatch)
//
// ROUND 10 = DIAGNOSTIC: k_proto is dispatched TWICE (all stores idempotent,
// stream-serialized; first instance's out-zero goes to dummyOut). The dur_us
// delta vs round 9 measures standalone k_proto cost + per-dispatch overhead.

// ---------------------------------------------------------------------------
// K1: per-(b,d,chunk) prototype partial sums (predicated cndmask accumulate).
// grid = Bn*Dn*PS = 2048 blocks, 256 threads. Blocks with d<2 also count
// labels (ballot/popc) + mask sum for slice s = chunk*2+d (2048 px).
// ---------------------------------------------------------------------------
__global__ __launch_bounds__(256) void k_proto(
        const float* __restrict__ x,
        const int* __restrict__ label,
        const int* __restrict__ mask,
        float* __restrict__ protoPart,   // [Bn][PS][Dn][Cn]
        float* __restrict__ countsPart,  // [Bn][CS][Cn]
        float* __restrict__ maskPart,    // [Bn][CS]
        float* __restrict__ out) {
    int bid = blockIdx.x;
    int chunk = bid & (PS - 1);
    int d = (bid >> 2) & (Dn - 1);
    int b = bid >> 9;               // Dn*PS = 512 blocks per batch
    int tid = threadIdx.x;
    int wid = tid >> 6, lane = tid & 63;

    if (bid == 0 && tid == 0) out[0] = 0.f;   // k_main atomicAdds later

    constexpr int CH = NPIX / PS;   // 4096 pixels per block
    const float4* xp = (const float4*)(x + (size_t)(b * Dn + d) * NPIX + chunk * CH);
    const int4*   lp = (const int4*)(label + (size_t)b * NPIX + chunk * CH);

    float acc[Cn];
#pragma unroll
    for (int c = 0; c < Cn; ++c) acc[c] = 0.f;

#pragma unroll
    for (int i = tid; i < CH / 4; i += 256) {   // 4 iterations
        float4 xv = xp[i];
        int4 lv = lp[i];
        int l0 = lv.x - 1, l1 = lv.y - 1, l2 = lv.z - 1, l3 = lv.w - 1;
#pragma unroll
        for (int c = 0; c < Cn; ++c) {
            acc[c] += ((l0 == c) ? xv.x : 0.f) + ((l1 == c) ? xv.y : 0.f)
                    + ((l2 == c) ? xv.z : 0.f) + ((l3 == c) ? xv.w : 0.f);
        }
    }

#pragma unroll
    for (int c = 0; c < Cn; ++c)
        for (int off = 32; off; off >>= 1) acc[c] += __shfl_down(acc[c], off);

    __shared__ float red[4][Cn];
    if (lane == 0) {
#pragma unroll
        for (int c = 0; c < Cn; ++c) red[wid][c] = acc[c];
    }
    __syncthreads();
    if (tid < Cn) {
        float s = red[0][tid] + red[1][tid] + red[2][tid] + red[3][tid];
        protoPart[(((size_t)(b * PS + chunk)) * Dn + d) * Cn + tid] = s;
    }

    if (d < 2) {   // block-uniform: counts + mask for slice s (2048 px)
        int s = chunk * 2 + d;
        const int4* lp2 = (const int4*)(label + (size_t)b * NPIX + s * 2048);
        const int4* mp2 = (const int4*)(mask  + (size_t)b * NPIX + s * 2048);
        int cnt[Cn];
#pragma unroll
        for (int c = 0; c < Cn; ++c) cnt[c] = 0;
        int msum = 0;
#pragma unroll
        for (int i = tid; i < 512; i += 256) {   // 2 iterations
            int4 lv = lp2[i];
            int4 mv = mp2[i];
            msum += mv.x + mv.y + mv.z + mv.w;
            int l0 = lv.x - 1, l1 = lv.y - 1, l2 = lv.z - 1, l3 = lv.w - 1;
#pragma unroll
            for (int c = 0; c < Cn; ++c) {
                cnt[c] += (int)__popcll(__ballot(l0 == c))
                        + (int)__popcll(__ballot(l1 == c))
                        + (int)__popcll(__ballot(l2 == c))
                        + (int)__popcll(__ballot(l3 == c));
            }
        }
        for (int off = 32; off; off >>= 1) msum += __shfl_down(msum, off);

        __shared__ int redi[4][Cn + 1];
        if (lane == 0) {
#pragma unroll
            for (int c = 0; c < Cn; ++c) redi[wid][c] = cnt[c];
            redi[wid][Cn] = msum;
        }
        __syncthreads();
        if (tid < Cn) {
            int t = redi[0][tid] + redi[1][tid] + redi[2][tid] + redi[3][tid];
            countsPart[((size_t)b * CS + s) * Cn + tid] = (float)t;
        } else if (tid == Cn) {
            int t = redi[0][Cn] + redi[1][Cn] + redi[2][Cn] + redi[3][Cn];
            maskPart[b * CS + s] = (float)t;
        }
    }
}

// ---------------------------------------------------------------------------
// K2: metric + CE (unchanged from round 9).
// ---------------------------------------------------------------------------
__global__ __launch_bounds__(256, 4) void k_main(
        const float* __restrict__ x,
        const int* __restrict__ label,
        const int* __restrict__ mask,
        const float* __restrict__ protoPart,  // [Bn][PS][Dn][Cn]
        const float* __restrict__ countsPart, // [Bn][CS][Cn]
        const float* __restrict__ maskPart,   // [Bn][CS]
        float* __restrict__ out) {
    int b = blockIdx.x >> 7;                 // 128 blocks per batch
    int pbase = (blockIdx.x & 127) << 7;     // 128 pixels per block
    int tid = threadIdx.x;
    int lx = tid & 63, dg = tid >> 6;        // lane-x (pixel pair), d-group

    __shared__ float smem[4 * Cn * 128];     // 32 KB, aliased proto/part
    __shared__ float cntInv[Cn];
    __shared__ float shInvMask;
    __shared__ float r2[2];
    float (*proto)[Cn] = (float (*)[Cn])smem;          // [Dn][Cn]
    float (*part)[Cn][128] = (float (*)[Cn][128])smem; // [4][Cn][128]

    if (tid < Cn) {
        float s = 0.f;
#pragma unroll
        for (int q = 0; q < CS; ++q)
            s += countsPart[((size_t)b * CS + q) * Cn + tid];
        cntInv[tid] = 1.f / s;
    } else if (tid == Cn) {
        float ms = 0.f;
#pragma unroll
        for (int q = 0; q < CS; ++q) ms += maskPart[b * CS + q];
        shInvMask = 1.f / ms;
    }
    __syncthreads();

    {
        const float* pp = protoPart + (size_t)b * PS * Dn * Cn;
        for (int i = tid; i < Dn * Cn; i += 256) {
            int c = i & (Cn - 1);
            float s = pp[i] + pp[Dn * Cn + i] + pp[2 * Dn * Cn + i]
                    + pp[3 * Dn * Cn + i];
            smem[i] = s * cntInv[c];
        }
    }
    __syncthreads();

    float2 acc[Cn];
#pragma unroll
    for (int c = 0; c < Cn; ++c) acc[c] = make_float2(0.f, 0.f);

    const float2* xp = (const float2*)(x + (size_t)b * Dn * NPIX + pbase) + lx;
#pragma unroll 2
    for (int dd = 0; dd < 32; ++dd) {
        int d = (dg << 5) + dd;
        float2 xv = xp[(size_t)d * (NPIX / 2)];
        float4 q0 = *(const float4*)&proto[d][0];
        float4 q1 = *(const float4*)&proto[d][4];
        float4 q2 = *(const float4*)&proto[d][8];
        float4 q3 = *(const float4*)&proto[d][12];
        acc[0].x  += fabsf(xv.x - q0.x);  acc[0].y  += fabsf(xv.y - q0.x);
        acc[1].x  += fabsf(xv.x - q0.y);  acc[1].y  += fabsf(xv.y - q0.y);
        acc[2].x  += fabsf(xv.x - q0.z);  acc[2].y  += fabsf(xv.y - q0.z);
        acc[3].x  += fabsf(xv.x - q0.w);  acc[3].y  += fabsf(xv.y - q0.w);
        acc[4].x  += fabsf(xv.x - q1.x);  acc[4].y  += fabsf(xv.y - q1.x);
        acc[5].x  += fabsf(xv.x - q1.y);  acc[5].y  += fabsf(xv.y - q1.y);
        acc[6].x  += fabsf(xv.x - q1.z);  acc[6].y  += fabsf(xv.y - q1.z);
        acc[7].x  += fabsf(xv.x - q1.w);  acc[7].y  += fabsf(xv.y - q1.w);
        acc[8].x  += fabsf(xv.x - q2.x);  acc[8].y  += fabsf(xv.y - q2.x);
        acc[9].x  += fabsf(xv.x - q2.y);  acc[9].y  += fabsf(xv.y - q2.y);
        acc[10].x += fabsf(xv.x - q2.z);  acc[10].y += fabsf(xv.y - q2.z);
        acc[11].x += fabsf(xv.x - q2.w);  acc[11].y += fabsf(xv.y - q2.w);
        acc[12].x += fabsf(xv.x - q3.x);  acc[12].y += fabsf(xv.y - q3.x);
        acc[13].x += fabsf(xv.x - q3.y);  acc[13].y += fabsf(xv.y - q3.y);
        acc[14].x += fabsf(xv.x - q3.z);  acc[14].y += fabsf(xv.y - q3.z);
        acc[15].x += fabsf(xv.x - q3.w);  acc[15].y += fabsf(xv.y - q3.w);
    }

    __syncthreads();   // all proto reads done -> smem reusable as part[]

#pragma unroll
    for (int c = 0; c < Cn; ++c)
        *(float2*)&part[dg][c][lx * 2] = acc[c];
    __syncthreads();

    float v = 0.f;
    if (tid < 128) {
        float a[Cn];
#pragma unroll
        for (int c = 0; c < Cn; ++c)
            a[c] = part[0][c][tid] + part[1][c][tid]
                 + part[2][c][tid] + part[3][c][tid];

        float pd0[Cn];
        float mn = 3.4e38f;
#pragma unroll
        for (int c = 0; c < Cn; ++c) {
            pd0[c] = __expf(-a[c]);
            mn = fminf(mn, pd0[c]);
        }
        float se = 0.f;
#pragma unroll
        for (int c = 0; c < Cn; ++c) se += __expf(pd0[c] - mn);

        int p = pbase + tid;
        int l = label[b * NPIX + p] - 1;
        float pdl = 0.f;
#pragma unroll
        for (int c = 0; c < Cn; ++c) pdl = (l == c) ? (pd0[c] - mn) : pdl;

        float ce = __logf(se) - pdl;
        float m = (float)mask[b * NPIX + p];
        v = ce * m;

        for (int off = 32; off; off >>= 1) v += __shfl_down(v, off);
        if ((tid & 63) == 0) r2[tid >> 6] = v;
    }
    __syncthreads();
    if (tid == 0) atomicAdd(out, (r2[0] + r2[1]) * shInvMask);
}

extern "C" void kernel_launch(void* const* d_in, const int* in_sizes, int n_in,
                              void* d_out, int out_size, void* d_ws, size_t ws_size,
                              hipStream_t stream) {
    const float* x     = (const float*)d_in[0];  // [B,D,H,W] f32
    const int*   label = (const int*)d_in[1];    // [B,H,W]
    const int*   mask  = (const int*)d_in[2];    // [B,1,H,W]
    float* out = (float*)d_out;

    float* ws         = (float*)d_ws;
    float* protoPart  = ws;                               // 32768
    float* countsPart = protoPart + Bn * PS * Dn * Cn;    // 512
    float* maskPart   = countsPart + Bn * CS * Cn;        // 32
    float* dummyOut   = maskPart + Bn * CS;               // 1 (probe sink)

    // DIAGNOSTIC duplicate: identical work, idempotent stores, out -> dummy.
    k_proto<<<Bn * Dn * PS, 256, 0, stream>>>(x, label, mask, protoPart,
                                              countsPart, maskPart, dummyOut);
    k_proto<<<Bn * Dn * PS, 256, 0, stream>>>(x, label, mask, protoPart,
                                              countsPart, maskPart, out);
    k_main <<<Bn * (NPIX / 128), 256, 0, stream>>>(x, label, mask, protoPart,
                                                   countsPart, maskPart, out);
}

// Round 11
// 34.385 us; speedup vs baseline: 1.5454x; 1.5454x over previous
//
#include <hip/hip_runtime.h>

// Problem constants (match reference)
constexpr int Bn = 4, Dn = 128, Hn = 128, Wn = 128, Cn = 16;
constexpr int NPIX = Hn * Wn;  // 16384
constexpr int PS = 4;          // proto pixel-chunks per (b,d)
constexpr int CS = 8;          // count slices per batch (2048 px each)
constexpr int HP = 17;         // hist row pad (odd -> full bank spread)

// ws layout (floats), all plain stores every call, no zero-init, no memsets:
//   protoPart [Bn][PS][Dn][Cn] = 32768
//   countsPart[Bn][CS][Cn]     = 512
//   maskPart  [Bn][CS]         = 32
// out[0] zeroed by k_proto block 0; k_main atomicAdds per-block contributions.

// ---------------------------------------------------------------------------
// K1: per-(b,d,chunk) prototype partial sums via PRIVATIZED LDS HISTOGRAM:
// each thread owns hist[tid][0..15] (17-padded row). Per pixel: one
// ds_read + v_add + ds_write to the thread's own slot -- no atomics, no
// same-address serialization (R4's failure was ds_add atomics), ~2-way
// bank alias worst case (free). Replaces the 48-VALU-ops/px predicated
// cndmask scatter (R10 probe: 13.4 us, 2.6x over VALU floor).
// grid = Bn*Dn*PS = 2048 blocks, 256 threads -> 8 blocks/CU, 32 waves/CU.
// Blocks with d<2 also count labels (ballot/popc) + mask sum for slice
// s = chunk*2+d (2048 px).
// ---------------------------------------------------------------------------
__global__ __launch_bounds__(256, 8) void k_proto(
        const float* __restrict__ x,
        const int* __restrict__ label,
        const int* __restrict__ mask,
        float* __restrict__ protoPart,   // [Bn][PS][Dn][Cn]
        float* __restrict__ countsPart,  // [Bn][CS][Cn]
        float* __restrict__ maskPart,    // [Bn][CS]
        float* __restrict__ out) {
    int bid = blockIdx.x;
    int chunk = bid & (PS - 1);
    int d = (bid >> 2) & (Dn - 1);
    int b = bid >> 9;               // Dn*PS = 512 blocks per batch
    int tid = threadIdx.x;
    int wid = tid >> 6, lane = tid & 63;

    if (bid == 0 && tid == 0) out[0] = 0.f;   // k_main atomicAdds later

    __shared__ float hist[256 * HP];   // 17 KB, thread-private rows
    for (int i = tid; i < 256 * HP; i += 256) hist[i] = 0.f;
    __syncthreads();

    constexpr int CH = NPIX / PS;   // 4096 pixels per block
    const float4* xp = (const float4*)(x + (size_t)(b * Dn + d) * NPIX + chunk * CH);
    const int4*   lp = (const int4*)(label + (size_t)b * NPIX + chunk * CH);

    float* h = &hist[tid * HP];
#pragma unroll
    for (int i = tid; i < CH / 4; i += 256) {   // 4 iterations, loads hoisted
        float4 xv = xp[i];
        int4 lv = lp[i];
        h[lv.x - 1] += xv.x;
        h[lv.y - 1] += xv.y;
        h[lv.z - 1] += xv.z;
        h[lv.w - 1] += xv.w;
    }
    __syncthreads();

    // reduce 256 rows -> 16 class sums.
    // phase A: thread t (c = t&15, g = t>>4) sums rows [16g, 16g+16) for c.
    {
        int c = tid & 15, g = tid >> 4;
        float s = 0.f;
#pragma unroll
        for (int i = 0; i < 16; ++i) s += hist[(g * 16 + i) * HP + c];
        // wave-local: combine the wave's 4 g-groups (lanes ^16, ^32 share c)
        s += __shfl_xor(s, 16);
        s += __shfl_xor(s, 32);
        __shared__ float red[4][Cn];
        if (lane < Cn) red[wid][lane] = s;
        __syncthreads();
        if (tid < Cn) {
            float t4 = red[0][tid] + red[1][tid] + red[2][tid] + red[3][tid];
            protoPart[(((size_t)(b * PS + chunk)) * Dn + d) * Cn + tid] = t4;
        }
    }

    if (d < 2) {   // block-uniform: counts + mask for slice s (2048 px)
        int s = chunk * 2 + d;
        const int4* lp2 = (const int4*)(label + (size_t)b * NPIX + s * 2048);
        const int4* mp2 = (const int4*)(mask  + (size_t)b * NPIX + s * 2048);
        int cnt[Cn];
#pragma unroll
        for (int c = 0; c < Cn; ++c) cnt[c] = 0;
        int msum = 0;
#pragma unroll
        for (int i = tid; i < 512; i += 256) {   // 2 iterations
            int4 lv = lp2[i];
            int4 mv = mp2[i];
            msum += mv.x + mv.y + mv.z + mv.w;
            int l0 = lv.x - 1, l1 = lv.y - 1, l2 = lv.z - 1, l3 = lv.w - 1;
#pragma unroll
            for (int c = 0; c < Cn; ++c) {
                cnt[c] += (int)__popcll(__ballot(l0 == c))
                        + (int)__popcll(__ballot(l1 == c))
                        + (int)__popcll(__ballot(l2 == c))
                        + (int)__popcll(__ballot(l3 == c));
            }
        }
        for (int off = 32; off; off >>= 1) msum += __shfl_down(msum, off);

        __shared__ int redi[4][Cn + 1];
        if (lane == 0) {
#pragma unroll
            for (int c = 0; c < Cn; ++c) redi[wid][c] = cnt[c];
            redi[wid][Cn] = msum;
        }
        __syncthreads();
        if (tid < Cn) {
            int t = redi[0][tid] + redi[1][tid] + redi[2][tid] + redi[3][tid];
            countsPart[((size_t)b * CS + s) * Cn + tid] = (float)t;
        } else if (tid == Cn) {
            int t = redi[0][Cn] + redi[1][Cn] + redi[2][Cn] + redi[3][Cn];
            maskPart[b * CS + s] = (float)t;
        }
    }
}

// ---------------------------------------------------------------------------
// K2: metric + CE (unchanged from round 9).
// ---------------------------------------------------------------------------
__global__ __launch_bounds__(256, 4) void k_main(
        const float* __restrict__ x,
        const int* __restrict__ label,
        const int* __restrict__ mask,
        const float* __restrict__ protoPart,  // [Bn][PS][Dn][Cn]
        const float* __restrict__ countsPart, // [Bn][CS][Cn]
        const float* __restrict__ maskPart,   // [Bn][CS]
        float* __restrict__ out) {
    int b = blockIdx.x >> 7;                 // 128 blocks per batch
    int pbase = (blockIdx.x & 127) << 7;     // 128 pixels per block
    int tid = threadIdx.x;
    int lx = tid & 63, dg = tid >> 6;        // lane-x (pixel pair), d-group

    __shared__ float smem[4 * Cn * 128];     // 32 KB, aliased proto/part
    __shared__ float cntInv[Cn];
    __shared__ float shInvMask;
    __shared__ float r2[2];
    float (*proto)[Cn] = (float (*)[Cn])smem;          // [Dn][Cn]
    float (*part)[Cn][128] = (float (*)[Cn][128])smem; // [4][Cn][128]

    if (tid < Cn) {
        float s = 0.f;
#pragma unroll
        for (int q = 0; q < CS; ++q)
            s += countsPart[((size_t)b * CS + q) * Cn + tid];
        cntInv[tid] = 1.f / s;
    } else if (tid == Cn) {
        float ms = 0.f;
#pragma unroll
        for (int q = 0; q < CS; ++q) ms += maskPart[b * CS + q];
        shInvMask = 1.f / ms;
    }
    __syncthreads();

    {
        const float* pp = protoPart + (size_t)b * PS * Dn * Cn;
        for (int i = tid; i < Dn * Cn; i += 256) {
            int c = i & (Cn - 1);
            float s = pp[i] + pp[Dn * Cn + i] + pp[2 * Dn * Cn + i]
                    + pp[3 * Dn * Cn + i];
            smem[i] = s * cntInv[c];
        }
    }
    __syncthreads();

    float2 acc[Cn];
#pragma unroll
    for (int c = 0; c < Cn; ++c) acc[c] = make_float2(0.f, 0.f);

    const float2* xp = (const float2*)(x + (size_t)b * Dn * NPIX + pbase) + lx;
#pragma unroll 2
    for (int dd = 0; dd < 32; ++dd) {
        int d = (dg << 5) + dd;
        float2 xv = xp[(size_t)d * (NPIX / 2)];
        float4 q0 = *(const float4*)&proto[d][0];
        float4 q1 = *(const float4*)&proto[d][4];
        float4 q2 = *(const float4*)&proto[d][8];
        float4 q3 = *(const float4*)&proto[d][12];
        acc[0].x  += fabsf(xv.x - q0.x);  acc[0].y  += fabsf(xv.y - q0.x);
        acc[1].x  += fabsf(xv.x - q0.y);  acc[1].y  += fabsf(xv.y - q0.y);
        acc[2].x  += fabsf(xv.x - q0.z);  acc[2].y  += fabsf(xv.y - q0.z);
        acc[3].x  += fabsf(xv.x - q0.w);  acc[3].y  += fabsf(xv.y - q0.w);
        acc[4].x  += fabsf(xv.x - q1.x);  acc[4].y  += fabsf(xv.y - q1.x);
        acc[5].x  += fabsf(xv.x - q1.y);  acc[5].y  += fabsf(xv.y - q1.y);
        acc[6].x  += fabsf(xv.x - q1.z);  acc[6].y  += fabsf(xv.y - q1.z);
        acc[7].x  += fabsf(xv.x - q1.w);  acc[7].y  += fabsf(xv.y - q1.w);
        acc[8].x  += fabsf(xv.x - q2.x);  acc[8].y  += fabsf(xv.y - q2.x);
        acc[9].x  += fabsf(xv.x - q2.y);  acc[9].y  += fabsf(xv.y - q2.y);
        acc[10].x += fabsf(xv.x - q2.z);  acc[10].y += fabsf(xv.y - q2.z);
        acc[11].x += fabsf(xv.x - q2.w);  acc[11].y += fabsf(xv.y - q2.w);
        acc[12].x += fabsf(xv.x - q3.x);  acc[12].y += fabsf(xv.y - q3.x);
        acc[13].x += fabsf(xv.x - q3.y);  acc[13].y += fabsf(xv.y - q3.y);
        acc[14].x += fabsf(xv.x - q3.z);  acc[14].y += fabsf(xv.y - q3.z);
        acc[15].x += fabsf(xv.x - q3.w);  acc[15].y += fabsf(xv.y - q3.w);
    }

    __syncthreads();   // all proto reads done -> smem reusable as part[]

#pragma unroll
    for (int c = 0; c < Cn; ++c)
        *(float2*)&part[dg][c][lx * 2] = acc[c];
    __syncthreads();

    float v = 0.f;
    if (tid < 128) {
        float a[Cn];
#pragma unroll
        for (int c = 0; c < Cn; ++c)
            a[c] = part[0][c][tid] + part[1][c][tid]
                 + part[2][c][tid] + part[3][c][tid];

        float pd0[Cn];
        float mn = 3.4e38f;
#pragma unroll
        for (int c = 0; c < Cn; ++c) {
            pd0[c] = __expf(-a[c]);
            mn = fminf(mn, pd0[c]);
        }
        float se = 0.f;
#pragma unroll
        for (int c = 0; c < Cn; ++c) se += __expf(pd0[c] - mn);

        int p = pbase + tid;
        int l = label[b * NPIX + p] - 1;
        float pdl = 0.f;
#pragma unroll
        for (int c = 0; c < Cn; ++c) pdl = (l == c) ? (pd0[c] - mn) : pdl;

        float ce = __logf(se) - pdl;
        float m = (float)mask[b * NPIX + p];
        v = ce * m;

        for (int off = 32; off; off >>= 1) v += __shfl_down(v, off);
        if ((tid & 63) == 0) r2[tid >> 6] = v;
    }
    __syncthreads();
    if (tid == 0) atomicAdd(out, (r2[0] + r2[1]) * shInvMask);
}

extern "C" void kernel_launch(void* const* d_in, const int* in_sizes, int n_in,
                              void* d_out, int out_size, void* d_ws, size_t ws_size,
                              hipStream_t stream) {
    const float* x     = (const float*)d_in[0];  // [B,D,H,W] f32
    const int*   label = (const int*)d_in[1];    // [B,H,W]
    const int*   mask  = (const int*)d_in[2];    // [B,1,H,W]
    float* out = (float*)d_out;

    float* ws         = (float*)d_ws;
    float* protoPart  = ws;                               // 32768
    float* countsPart = protoPart + Bn * PS * Dn * Cn;    // 512
    float* maskPart   = countsPart + Bn * CS * Cn;        // 32

    k_proto<<<Bn * Dn * PS, 256, 0, stream>>>(x, label, mask, protoPart,
                                              countsPart, maskPart, out);
    k_main <<<Bn * (NPIX / 128), 256, 0, stream>>>(x, label, mask, protoPart,
                                                   countsPart, maskPart, out);
}